// Round 2
// baseline (853.629 us; speedup 1.0000x reference)
//
#include <hip/hip_runtime.h>
#include <stdint.h>

#define N_NODES 50000
#define N_EDGES 600000
#define N_REL   8

typedef short v8s __attribute__((ext_vector_type(8)));
typedef float v4f __attribute__((ext_vector_type(4)));
typedef unsigned short u16;
typedef unsigned int   u32;

__device__ __forceinline__ float bf2f(u16 u) {
    union { u32 i; float f; } t; t.i = ((u32)u) << 16; return t.f;
}
__device__ __forceinline__ u16 f2bf(float f) {
    union { float f; u32 i; } t; t.f = f;
    u32 lsb = (t.i >> 16) & 1u;
    t.i += 0x7fffu + lsb;            // round-to-nearest-even
    return (u16)(t.i >> 16);
}

// ---------- dtype detection: bf16 vs f32 input tensors ----------
// For each 32-bit word, bits[14:7] of the LOW halfword are the exponent field
// if data is bf16 (concentrated near 127 for N(0,1)), or random mantissa bits
// if data is f32 (uniform). Count in-range fraction over 1024 words.
__global__ void k_detect(const u32* __restrict__ x, int* __restrict__ flag) {
    __shared__ int cnt;
    int tid = threadIdx.x;
    if (tid == 0) cnt = 0;
    __syncthreads();
    int local = 0;
    for (int j = 0; j < 4; ++j) {
        u32 w = x[tid * 4 + j];
        u32 e = (w >> 7) & 0xffu;
        if (e >= 112u && e < 144u) local++;
    }
    atomicAdd(&cnt, local);
    __syncthreads();
    if (tid == 0) *flag = (cnt >= 512) ? 1 : 0;   // 1 = bf16, 0 = f32
}

// canonicalize any float tensor to bf16
__global__ void k_convert(const void* __restrict__ src, u16* __restrict__ dst, int n,
                          const int* __restrict__ flag) {
    int i = blockIdx.x * 256 + threadIdx.x;
    if (i >= n) return;
    if (*flag) dst[i] = ((const u16*)src)[i];
    else       dst[i] = f2bf(((const float*)src)[i]);
}

// ---------- weight prep ----------
// Wtp[l][p][j][k2] = W_l[2p + k2/128][k2%128][j]   (pair-batched, B as [n][k])
// Wtr[l][j][k]     = root_l[k][j]
__global__ void k_prep_w(const u16* __restrict__ w1c, const u16* __restrict__ r1c,
                         const u16* __restrict__ w2c, const u16* __restrict__ r2c,
                         u16* __restrict__ Wtp, u16* __restrict__ Wtr) {
    int o = blockIdx.x * 256 + threadIdx.x;
    if (o >= 294912) return;
    if (o < 262144) {
        int k2 = o & 255, j = (o >> 8) & 127, p = (o >> 15) & 3, l = o >> 17;
        const u16* w = l ? w2c : w1c;
        int r = 2 * p + (k2 >> 7), k = k2 & 127;
        Wtp[(size_t)((l * 4 + p) * 128 + j) * 256 + k2] = w[r * 16384 + k * 128 + j];
    } else {
        int o2 = o - 262144;
        int k = o2 & 127, j = (o2 >> 7) & 127, l = o2 >> 14;
        const u16* w = l ? r2c : r1c;
        Wtr[l * 16384 + j * 128 + k] = w[k * 128 + j];
    }
}

// ---------- graph prep ----------
__global__ void k_zero_i32(int* __restrict__ p, int n) {
    int i = blockIdx.x * 256 + threadIdx.x;
    if (i < n) p[i] = 0;
}

__global__ void k_count(const int* __restrict__ ei, int* __restrict__ deg) {
    int i = blockIdx.x * 256 + threadIdx.x;
    if (i >= N_EDGES) return;
    atomicAdd(&deg[ei[N_EDGES + i]], 1);
}

// single-block scan -> exclusive rowptr over N_NODES
__global__ void k_scan(const int* __restrict__ deg, int* __restrict__ rowptr) {
    __shared__ int lds[1024];
    __shared__ int carry;
    int tid = threadIdx.x;
    if (tid == 0) { carry = 0; rowptr[0] = 0; }
    __syncthreads();
    for (int base = 0; base < N_NODES; base += 1024) {
        int idx = base + tid;
        int v = (idx < N_NODES) ? deg[idx] : 0;
        lds[tid] = v;
        __syncthreads();
        for (int off = 1; off < 1024; off <<= 1) {
            int t = (tid >= off) ? lds[tid - off] : 0;
            __syncthreads();
            lds[tid] += t;
            __syncthreads();
        }
        if (idx < N_NODES) rowptr[idx + 1] = carry + lds[tid];
        int total = lds[1023];
        __syncthreads();
        if (tid == 0) carry += total;
        __syncthreads();
    }
}

__global__ void k_fill(const int* __restrict__ ei, const int* __restrict__ et,
                       const int* __restrict__ rowptr, int* __restrict__ cursor,
                       int* __restrict__ eval) {
    int i = blockIdx.x * 256 + threadIdx.x;
    if (i >= N_EDGES) return;
    int d = ei[N_EDGES + i];
    int pos = atomicAdd(&cursor[d], 1);
    eval[rowptr[d] + pos] = (ei[i] << 3) | et[i];
}

// ---------- aggregation for one relation PAIR p: agg2[n] = [mean_r(2p), mean_r(2p+1)] ----------
__global__ __launch_bounds__(256) void k_agg_pair(
        const u16* __restrict__ feat, const int* __restrict__ rowptr,
        const int* __restrict__ eval, u16* __restrict__ agg2, int p) {
    int wave = threadIdx.x >> 6, lane = threadIdx.x & 63;
    int node = blockIdx.x * 4 + wave;
    if (node >= N_NODES) return;
    int c2 = lane * 2;
    float a0x = 0.f, a0y = 0.f, a1x = 0.f, a1y = 0.f;
    int c0 = 0, c1 = 0;
    int s = rowptr[node], e = rowptr[node + 1];
    for (int i = s; i < e; ++i) {
        int ev = eval[i];
        int r = ev & 7;
        if ((r >> 1) != p) continue;                 // wave-uniform branch
        ushort2 u = *(const ushort2*)(feat + (size_t)(ev >> 3) * 128 + c2);
        if (r & 1) { a1x += bf2f(u.x); a1y += bf2f(u.y); c1++; }
        else       { a0x += bf2f(u.x); a0y += bf2f(u.y); c0++; }
    }
    float i0 = 1.f / (float)(c0 > 0 ? c0 : 1);
    float i1 = 1.f / (float)(c1 > 0 ? c1 : 1);
    u16* d0 = agg2 + (size_t)node * 256 + c2;
    ushort2 o0; o0.x = f2bf(a0x * i0); o0.y = f2bf(a0y * i0);
    ushort2 o1; o1.x = f2bf(a1x * i1); o1.y = f2bf(a1y * i1);
    *(ushort2*)d0 = o0;
    *(ushort2*)(d0 + 128) = o1;
}

// ---------- GEMM (K=256): acc (f32) = or += agg2 @ [W_2p ; W_2p+1] ----------
__global__ __launch_bounds__(256, 2) void k_gemm_pair(
        const u16* __restrict__ A,      // [N,256] bf16
        const u16* __restrict__ B,      // [128][256] bf16 (n-major, k contiguous)
        float* __restrict__ acc, int first) {
    __shared__ u16 As[128 * 128];
    __shared__ u16 Bs[128 * 128];
    int tid = threadIdx.x;
    int bm0 = blockIdx.x * 128;
    int wave = tid >> 6, lane = tid & 63;
    int wm = (wave & 1) * 64, wn = (wave >> 1) * 64;
    int lrow = lane & 15, quad = lane >> 4;

    v4f accr[4][4];
    #pragma unroll
    for (int i = 0; i < 4; ++i)
        #pragma unroll
        for (int j = 0; j < 4; ++j) accr[i][j] = (v4f){0.f, 0.f, 0.f, 0.f};

    for (int half = 0; half < 2; ++half) {
        if (half) __syncthreads();      // WAR: previous MFMA reads done
        #pragma unroll
        for (int it = 0; it < 8; ++it) {
            int c = it * 256 + tid;
            int row = c >> 4, cc = c & 15, swz = cc ^ (row & 15);
            int grow = bm0 + row;
            int4 va = make_int4(0, 0, 0, 0);
            if (grow < N_NODES) va = *(const int4*)(A + (size_t)grow * 256 + half * 128 + cc * 8);
            *(int4*)(As + row * 128 + swz * 8) = va;
            int4 vb = *(const int4*)(B + (size_t)row * 256 + half * 128 + cc * 8);
            *(int4*)(Bs + row * 128 + swz * 8) = vb;
        }
        __syncthreads();

        #pragma unroll
        for (int kk = 0; kk < 4; ++kk) {
            int chunk = kk * 4 + quad;
            int sw = (chunk ^ lrow) * 8;
            v8s a[4], b[4];
            #pragma unroll
            for (int t = 0; t < 4; ++t) a[t] = *(const v8s*)(As + (wm + t * 16 + lrow) * 128 + sw);
            #pragma unroll
            for (int t = 0; t < 4; ++t) b[t] = *(const v8s*)(Bs + (wn + t * 16 + lrow) * 128 + sw);
            #pragma unroll
            for (int ti = 0; ti < 4; ++ti)
                #pragma unroll
                for (int tj = 0; tj < 4; ++tj)
                    accr[ti][tj] = __builtin_amdgcn_mfma_f32_16x16x32_bf16(a[ti], b[tj], accr[ti][tj], 0, 0, 0);
        }
    }

    #pragma unroll
    for (int ti = 0; ti < 4; ++ti)
        #pragma unroll
        for (int reg = 0; reg < 4; ++reg) {
            int gm = bm0 + wm + ti * 16 + quad * 4 + reg;
            if (gm >= N_NODES) continue;
            #pragma unroll
            for (int tj = 0; tj < 4; ++tj) {
                int col = wn + tj * 16 + lrow;
                size_t idx = (size_t)gm * 128 + col;
                float v = accr[ti][tj][reg];
                if (!first) v += acc[idx];
                acc[idx] = v;
            }
        }
}

// ---------- root GEMM (K=128) + acc + bias + relu + write ----------
__global__ __launch_bounds__(256, 2) void k_gemm_root(
        const u16* __restrict__ A,      // [N,128] bf16 (x or h)
        const u16* __restrict__ B,      // Wtr[l]: [128][128]
        const u16* __restrict__ bias,
        const float* __restrict__ acc,
        u16* __restrict__ hout, void* __restrict__ fout,
        int final_out, const int* __restrict__ flag) {
    __shared__ u16 As[128 * 128];
    __shared__ u16 Bs[128 * 128];
    int tid = threadIdx.x;
    int bm0 = blockIdx.x * 128;
    int wave = tid >> 6, lane = tid & 63;
    int wm = (wave & 1) * 64, wn = (wave >> 1) * 64;
    int lrow = lane & 15, quad = lane >> 4;
    int fl = *flag;

    #pragma unroll
    for (int it = 0; it < 8; ++it) {
        int c = it * 256 + tid;
        int row = c >> 4, cc = c & 15, swz = cc ^ (row & 15);
        int grow = bm0 + row;
        int4 va = make_int4(0, 0, 0, 0);
        if (grow < N_NODES) va = *(const int4*)(A + (size_t)grow * 128 + cc * 8);
        *(int4*)(As + row * 128 + swz * 8) = va;
        int4 vb = *(const int4*)(B + (size_t)row * 128 + cc * 8);
        *(int4*)(Bs + row * 128 + swz * 8) = vb;
    }
    __syncthreads();

    v4f accr[4][4];
    #pragma unroll
    for (int i = 0; i < 4; ++i)
        #pragma unroll
        for (int j = 0; j < 4; ++j) accr[i][j] = (v4f){0.f, 0.f, 0.f, 0.f};

    #pragma unroll
    for (int kk = 0; kk < 4; ++kk) {
        int chunk = kk * 4 + quad;
        int sw = (chunk ^ lrow) * 8;
        v8s a[4], b[4];
        #pragma unroll
        for (int t = 0; t < 4; ++t) a[t] = *(const v8s*)(As + (wm + t * 16 + lrow) * 128 + sw);
        #pragma unroll
        for (int t = 0; t < 4; ++t) b[t] = *(const v8s*)(Bs + (wn + t * 16 + lrow) * 128 + sw);
        #pragma unroll
        for (int ti = 0; ti < 4; ++ti)
            #pragma unroll
            for (int tj = 0; tj < 4; ++tj)
                accr[ti][tj] = __builtin_amdgcn_mfma_f32_16x16x32_bf16(a[ti], b[tj], accr[ti][tj], 0, 0, 0);
    }

    #pragma unroll
    for (int ti = 0; ti < 4; ++ti)
        #pragma unroll
        for (int reg = 0; reg < 4; ++reg) {
            int gm = bm0 + wm + ti * 16 + quad * 4 + reg;
            if (gm >= N_NODES) continue;
            #pragma unroll
            for (int tj = 0; tj < 4; ++tj) {
                int col = wn + tj * 16 + lrow;
                size_t idx = (size_t)gm * 128 + col;
                float v = accr[ti][tj][reg] + acc[idx] + bf2f(bias[col]);
                v = fmaxf(v, 0.f);
                if (!final_out)      hout[idx] = f2bf(v);
                else if (fl)         ((u16*)fout)[idx] = f2bf(v);
                else                 ((float*)fout)[idx] = v;
            }
        }
}

// rel_emb passthrough at flag-dependent dtype/offset
__global__ void k_relemb(const void* __restrict__ src, void* __restrict__ out,
                         const int* __restrict__ flag) {
    int i = blockIdx.x * 256 + threadIdx.x;
    if (i >= N_REL * 128) return;
    size_t o = (size_t)N_NODES * 128 + i;
    if (*flag) ((u16*)out)[o]   = ((const u16*)src)[i];
    else       ((float*)out)[o] = ((const float*)src)[i];
}

// ---------------- launch ----------------
static inline size_t align_up(size_t x, size_t a) { return (x + a - 1) & ~(a - 1); }

extern "C" void kernel_launch(void* const* d_in, const int* in_sizes, int n_in,
                              void* d_out, int out_size, void* d_ws, size_t ws_size,
                              hipStream_t stream) {
    const int* ei = (const int*)d_in[1];
    const int* et = (const int*)d_in[2];

    char* ws = (char*)d_ws;
    size_t off = 0;
    int* flag   = (int*)(ws + off);  off = align_up(off + 4, 256);
    u16* Wtp    = (u16*)(ws + off);  off = align_up(off + (size_t)2 * 4 * 128 * 256 * 2, 256);
    u16* Wtr    = (u16*)(ws + off);  off = align_up(off + (size_t)2 * 128 * 128 * 2, 256);
    u16* w1c    = (u16*)(ws + off);  off = align_up(off + (size_t)8 * 16384 * 2, 256);
    u16* r1c    = (u16*)(ws + off);  off = align_up(off + (size_t)16384 * 2, 256);
    u16* b1c    = (u16*)(ws + off);  off = align_up(off + 256, 256);
    u16* w2c    = (u16*)(ws + off);  off = align_up(off + (size_t)8 * 16384 * 2, 256);
    u16* r2c    = (u16*)(ws + off);  off = align_up(off + (size_t)16384 * 2, 256);
    u16* b2c    = (u16*)(ws + off);  off = align_up(off + 256, 256);
    u16* xc     = (u16*)(ws + off);  off = align_up(off + (size_t)N_NODES * 128 * 2, 256);
    int* deg    = (int*)(ws + off);  off += (size_t)N_NODES * 4;      // deg+cursor contiguous (one zero pass)
    int* cursor = (int*)(ws + off);  off = align_up(off + (size_t)N_NODES * 4, 256);
    int* rowptr = (int*)(ws + off);  off = align_up(off + (size_t)(N_NODES + 1) * 4, 256);
    int* eval   = (int*)(ws + off);  off = align_up(off + (size_t)N_EDGES * 4, 256);
    u16* agg2   = (u16*)(ws + off);  off = align_up(off + (size_t)N_NODES * 256 * 2, 256);
    float* acc  = (float*)(ws + off);off = align_up(off + (size_t)N_NODES * 128 * 4, 256);
    u16* h      = (u16*)(ws + off);  off = align_up(off + (size_t)N_NODES * 128 * 2, 256);
    (void)in_sizes; (void)n_in; (void)out_size; (void)ws_size;       // total ~81 MB

    k_detect<<<1, 256, 0, stream>>>((const u32*)d_in[0], flag);
    k_convert<<<(N_NODES * 128 + 255) / 256, 256, 0, stream>>>(d_in[0], xc, N_NODES * 128, flag);
    k_convert<<<512, 256, 0, stream>>>(d_in[3], w1c, 8 * 16384, flag);
    k_convert<<<64, 256, 0, stream>>>(d_in[4], r1c, 16384, flag);
    k_convert<<<1, 256, 0, stream>>>(d_in[5], b1c, 128, flag);
    k_convert<<<512, 256, 0, stream>>>(d_in[6], w2c, 8 * 16384, flag);
    k_convert<<<64, 256, 0, stream>>>(d_in[7], r2c, 16384, flag);
    k_convert<<<1, 256, 0, stream>>>(d_in[8], b2c, 128, flag);
    k_prep_w<<<1152, 256, 0, stream>>>(w1c, r1c, w2c, r2c, Wtp, Wtr);

    k_zero_i32<<<(2 * N_NODES + 255) / 256, 256, 0, stream>>>(deg, 2 * N_NODES);
    k_count<<<(N_EDGES + 255) / 256, 256, 0, stream>>>(ei, deg);
    k_scan<<<1, 1024, 0, stream>>>(deg, rowptr);
    k_fill<<<(N_EDGES + 255) / 256, 256, 0, stream>>>(ei, et, rowptr, cursor, eval);

    for (int l = 0; l < 2; ++l) {
        const u16* src = l ? h : xc;
        for (int p = 0; p < 4; ++p) {
            k_agg_pair<<<(N_NODES + 3) / 4, 256, 0, stream>>>(src, rowptr, eval, agg2, p);
            k_gemm_pair<<<(N_NODES + 127) / 128, 256, 0, stream>>>(
                agg2, Wtp + (size_t)(l * 4 + p) * 32768, acc, p == 0 ? 1 : 0);
        }
        k_gemm_root<<<(N_NODES + 127) / 128, 256, 0, stream>>>(
            src, Wtr + l * 16384, l ? b2c : b1c, acc, h, d_out, l, flag);
    }
    k_relemb<<<4, 256, 0, stream>>>(d_in[9], d_out, flag);
}

// Round 3
// 417.039 us; speedup vs baseline: 2.0469x; 2.0469x over previous
//
#include <hip/hip_runtime.h>
#include <stdint.h>

#define N_NODES 50000
#define N_EDGES 600000
#define N_REL   8
#define NB_SCAN ((N_NODES + 255) / 256)

typedef short v8s __attribute__((ext_vector_type(8)));
typedef float v4f __attribute__((ext_vector_type(4)));
typedef unsigned short u16;
typedef unsigned int   u32;

__device__ __forceinline__ float bf2f(u16 u) {
    union { u32 i; float f; } t; t.i = ((u32)u) << 16; return t.f;
}
__device__ __forceinline__ u16 f2bf(float f) {
    union { float f; u32 i; } t; t.f = f;
    u32 lsb = (t.i >> 16) & 1u;
    t.i += 0x7fffu + lsb;            // round-to-nearest-even
    return (u16)(t.i >> 16);
}
__device__ __forceinline__ float load_f(const void* p, int i, int fl) {
    return fl ? bf2f(((const u16*)p)[i]) : ((const float*)p)[i];
}

// ---------- dtype detection: bf16 vs f32 (bits[14:7] of low halfword = exponent if bf16) ----------
__global__ void k_detect(const u32* __restrict__ x, int* __restrict__ flag) {
    __shared__ int cnt;
    int tid = threadIdx.x;
    if (tid == 0) cnt = 0;
    __syncthreads();
    int local = 0;
    for (int j = 0; j < 4; ++j) {
        u32 e = (x[tid * 4 + j] >> 7) & 0xffu;
        if (e >= 112u && e < 144u) local++;
    }
    atomicAdd(&cnt, local);
    __syncthreads();
    if (tid == 0) *flag = (cnt >= 512) ? 1 : 0;   // 1 = bf16, 0 = f32
}

__global__ void k_convert(const void* __restrict__ src, u16* __restrict__ dst, int n,
                          const int* __restrict__ flag) {
    int i = blockIdx.x * 256 + threadIdx.x;
    if (i >= n) return;
    if (*flag) dst[i] = ((const u16*)src)[i];
    else       dst[i] = f2bf(((const float*)src)[i]);
}

// ---------- weight prep (reads raw inputs, flag-dispatched dtype) ----------
// Wstack[l][j][k] = W_l[k/128][k%128][j]  (k = r*128 + kk), 2*128*1024
// Wtr[l][j][k]    = root_l[k][j]
// bc[l][i]        = bias_l[i]
__global__ void k_prep_w(const void* __restrict__ W1, const void* __restrict__ r1,
                         const void* __restrict__ b1, const void* __restrict__ W2,
                         const void* __restrict__ r2, const void* __restrict__ b2,
                         const int* __restrict__ flag,
                         u16* __restrict__ Wstack, u16* __restrict__ Wtr,
                         u16* __restrict__ bc) {
    int o = blockIdx.x * 256 + threadIdx.x;
    int fl = *flag;
    if (o < 262144) {
        int l = o >> 17, rem = o & 0x1ffff;
        int j = rem >> 10, k = rem & 1023;
        int r = k >> 7, kk = k & 127;
        const void* w = l ? W2 : W1;
        Wstack[o] = f2bf(load_f(w, r * 16384 + kk * 128 + j, fl));
    } else if (o < 262144 + 32768) {
        int o2 = o - 262144;
        int l = o2 >> 14, rem = o2 & 0x3fff;
        int j = rem >> 7, k = rem & 127;
        Wtr[o2] = f2bf(load_f(l ? r2 : r1, k * 128 + j, fl));
    } else if (o < 262144 + 32768 + 256) {
        int o2 = o - 262144 - 32768;
        bc[o2] = f2bf(load_f((o2 >> 7) ? b2 : b1, o2 & 127, fl));
    }
}

// ---------- graph prep ----------
__global__ void k_zero_i32(int* __restrict__ p, int n) {
    int i = blockIdx.x * 256 + threadIdx.x;
    if (i < n) p[i] = 0;
}

__global__ void k_count(const int* __restrict__ ei, int* __restrict__ deg) {
    int i = blockIdx.x * 256 + threadIdx.x;
    if (i >= N_EDGES) return;
    atomicAdd(&deg[ei[N_EDGES + i]], 1);
}

// hierarchical scan: per-block inclusive scan + block sums
__global__ void k_scan1(const int* __restrict__ deg, int* __restrict__ rowptr,
                        int* __restrict__ psum) {
    __shared__ int lds[256];
    int tid = threadIdx.x;
    int idx = blockIdx.x * 256 + tid;
    int v = (idx < N_NODES) ? deg[idx] : 0;
    lds[tid] = v;
    __syncthreads();
    for (int off = 1; off < 256; off <<= 1) {
        int t = (tid >= off) ? lds[tid - off] : 0;
        __syncthreads();
        lds[tid] += t;
        __syncthreads();
    }
    if (idx < N_NODES) rowptr[idx + 1] = lds[tid];
    if (tid == 255) psum[blockIdx.x] = lds[255];
}

__global__ void k_scan2(int* __restrict__ psum) {
    __shared__ int lds[256];
    int tid = threadIdx.x;
    int v = (tid < NB_SCAN) ? psum[tid] : 0;
    lds[tid] = v;
    __syncthreads();
    for (int off = 1; off < 256; off <<= 1) {
        int t = (tid >= off) ? lds[tid - off] : 0;
        __syncthreads();
        lds[tid] += t;
        __syncthreads();
    }
    if (tid < NB_SCAN) psum[tid] = lds[tid] - v;   // exclusive
}

__global__ void k_scan3(int* __restrict__ rowptr, const int* __restrict__ psum) {
    int idx = blockIdx.x * 256 + threadIdx.x;
    if (idx < N_NODES) rowptr[idx + 1] += psum[blockIdx.x];
    if (idx == 0) rowptr[0] = 0;
}

__global__ void k_fill(const int* __restrict__ ei, const int* __restrict__ et,
                       const int* __restrict__ rowptr, int* __restrict__ cursor,
                       int* __restrict__ eval) {
    int i = blockIdx.x * 256 + threadIdx.x;
    if (i >= N_EDGES) return;
    int d = ei[N_EDGES + i];
    int pos = atomicAdd(&cursor[d], 1);
    eval[rowptr[d] + pos] = (ei[i] << 3) | et[i];
}

// ---------- merged aggregation: all 8 relation means per node, one pass over edges ----------
#define ACC_EDGE(EV, UX, UY) do {                                          \
    int r_ = (EV) & 7; float fx_ = bf2f(UX), fy_ = bf2f(UY);               \
    switch (r_) {                                                          \
    case 0: s0x += fx_; s0y += fy_; c0++; break;                           \
    case 1: s1x += fx_; s1y += fy_; c1++; break;                           \
    case 2: s2x += fx_; s2y += fy_; c2_++; break;                          \
    case 3: s3x += fx_; s3y += fy_; c3++; break;                           \
    case 4: s4x += fx_; s4y += fy_; c4++; break;                           \
    case 5: s5x += fx_; s5y += fy_; c5++; break;                           \
    case 6: s6x += fx_; s6y += fy_; c6++; break;                           \
    default: s7x += fx_; s7y += fy_; c7++; break;                          \
    } } while (0)

__global__ __launch_bounds__(256) void k_agg_all(
        const u16* __restrict__ feat, const int* __restrict__ rowptr,
        const int* __restrict__ eval, u16* __restrict__ aggAll) {
    int wave = threadIdx.x >> 6, lane = threadIdx.x & 63;
    int node = blockIdx.x * 4 + wave;
    if (node >= N_NODES) return;
    int c2 = lane * 2;
    float s0x=0,s0y=0,s1x=0,s1y=0,s2x=0,s2y=0,s3x=0,s3y=0;
    float s4x=0,s4y=0,s5x=0,s5y=0,s6x=0,s6y=0,s7x=0,s7y=0;
    int c0=0,c1=0,c2_=0,c3=0,c4=0,c5=0,c6=0,c7=0;
    int s = rowptr[node], e = rowptr[node + 1];
    int i = s;
    for (; i + 1 < e; i += 2) {
        int ev0 = eval[i], ev1 = eval[i + 1];
        ushort2 u0 = *(const ushort2*)(feat + ((ev0 >> 3) << 7) + c2);
        ushort2 u1 = *(const ushort2*)(feat + ((ev1 >> 3) << 7) + c2);
        ACC_EDGE(ev0, u0.x, u0.y);
        ACC_EDGE(ev1, u1.x, u1.y);
    }
    if (i < e) {
        int ev0 = eval[i];
        ushort2 u0 = *(const ushort2*)(feat + ((ev0 >> 3) << 7) + c2);
        ACC_EDGE(ev0, u0.x, u0.y);
    }
    u16* d = aggAll + node * 1024 + c2;
    float inv;
    ushort2 o;
    inv = 1.f / (float)(c0 > 0 ? c0 : 1); o.x = f2bf(s0x*inv); o.y = f2bf(s0y*inv); *(ushort2*)(d)       = o;
    inv = 1.f / (float)(c1 > 0 ? c1 : 1); o.x = f2bf(s1x*inv); o.y = f2bf(s1y*inv); *(ushort2*)(d + 128) = o;
    inv = 1.f / (float)(c2_> 0 ? c2_: 1); o.x = f2bf(s2x*inv); o.y = f2bf(s2y*inv); *(ushort2*)(d + 256) = o;
    inv = 1.f / (float)(c3 > 0 ? c3 : 1); o.x = f2bf(s3x*inv); o.y = f2bf(s3y*inv); *(ushort2*)(d + 384) = o;
    inv = 1.f / (float)(c4 > 0 ? c4 : 1); o.x = f2bf(s4x*inv); o.y = f2bf(s4y*inv); *(ushort2*)(d + 512) = o;
    inv = 1.f / (float)(c5 > 0 ? c5 : 1); o.x = f2bf(s5x*inv); o.y = f2bf(s5y*inv); *(ushort2*)(d + 640) = o;
    inv = 1.f / (float)(c6 > 0 ? c6 : 1); o.x = f2bf(s6x*inv); o.y = f2bf(s6y*inv); *(ushort2*)(d + 768) = o;
    inv = 1.f / (float)(c7 > 0 ? c7 : 1); o.x = f2bf(s7x*inv); o.y = f2bf(s7y*inv); *(ushort2*)(d + 896) = o;
}

// ---------- pair aggregation (fallback path) ----------
__global__ __launch_bounds__(256) void k_agg_pair(
        const u16* __restrict__ feat, const int* __restrict__ rowptr,
        const int* __restrict__ eval, u16* __restrict__ agg2, int p) {
    int wave = threadIdx.x >> 6, lane = threadIdx.x & 63;
    int node = blockIdx.x * 4 + wave;
    if (node >= N_NODES) return;
    int c2 = lane * 2;
    float a0x = 0.f, a0y = 0.f, a1x = 0.f, a1y = 0.f;
    int c0 = 0, c1 = 0;
    int s = rowptr[node], e = rowptr[node + 1];
    for (int i = s; i < e; ++i) {
        int ev = eval[i];
        int r = ev & 7;
        if ((r >> 1) != p) continue;
        ushort2 u = *(const ushort2*)(feat + ((ev >> 3) << 7) + c2);
        if (r & 1) { a1x += bf2f(u.x); a1y += bf2f(u.y); c1++; }
        else       { a0x += bf2f(u.x); a0y += bf2f(u.y); c0++; }
    }
    float i0 = 1.f / (float)(c0 > 0 ? c0 : 1);
    float i1 = 1.f / (float)(c1 > 0 ? c1 : 1);
    u16* d0 = agg2 + node * 256 + c2;
    ushort2 o0; o0.x = f2bf(a0x * i0); o0.y = f2bf(a0y * i0);
    ushort2 o1; o1.x = f2bf(a1x * i1); o1.y = f2bf(a1y * i1);
    *(ushort2*)d0 = o0;
    *(ushort2*)(d0 + 128) = o1;
}

// ---------- big GEMM (K=1024): out = relu(aggAll @ Wstack[l] + acc) ----------
__global__ __launch_bounds__(256, 2) void k_gemm_big(
        const u16* __restrict__ A,      // [N,1024]
        const u16* __restrict__ B,      // [128][1024] (n-major, k contiguous)
        const float* __restrict__ acc,  // [N,128] f32 (root + bias)
        u16* __restrict__ hout, void* __restrict__ fout,
        int final_out, const int* __restrict__ flag) {
    __shared__ u16 As[128 * 128];
    __shared__ u16 Bs[128 * 128];
    int tid = threadIdx.x;
    int bm0 = blockIdx.x * 128;
    int wave = tid >> 6, lane = tid & 63;
    int wm = (wave & 1) * 64, wn = (wave >> 1) * 64;
    int lrow = lane & 15, quad = lane >> 4;
    int fl = *flag;

    v4f accr[4][4];
    #pragma unroll
    for (int i = 0; i < 4; ++i)
        #pragma unroll
        for (int j = 0; j < 4; ++j) accr[i][j] = (v4f){0.f, 0.f, 0.f, 0.f};

    for (int half = 0; half < 8; ++half) {
        if (half) __syncthreads();
        #pragma unroll
        for (int it = 0; it < 8; ++it) {
            int c = it * 256 + tid;
            int row = c >> 4, cc = c & 15, swz = cc ^ (row & 15);
            int grow = bm0 + row;
            int4 va = make_int4(0, 0, 0, 0);
            if (grow < N_NODES) va = *(const int4*)(A + (size_t)grow * 1024 + half * 128 + cc * 8);
            *(int4*)(As + row * 128 + swz * 8) = va;
            int4 vb = *(const int4*)(B + (size_t)row * 1024 + half * 128 + cc * 8);
            *(int4*)(Bs + row * 128 + swz * 8) = vb;
        }
        __syncthreads();

        #pragma unroll
        for (int kk = 0; kk < 4; ++kk) {
            int chunk = kk * 4 + quad;
            int sw = (chunk ^ lrow) * 8;
            v8s a[4], b[4];
            #pragma unroll
            for (int t = 0; t < 4; ++t) a[t] = *(const v8s*)(As + (wm + t * 16 + lrow) * 128 + sw);
            #pragma unroll
            for (int t = 0; t < 4; ++t) b[t] = *(const v8s*)(Bs + (wn + t * 16 + lrow) * 128 + sw);
            #pragma unroll
            for (int ti = 0; ti < 4; ++ti)
                #pragma unroll
                for (int tj = 0; tj < 4; ++tj)
                    accr[ti][tj] = __builtin_amdgcn_mfma_f32_16x16x32_bf16(a[ti], b[tj], accr[ti][tj], 0, 0, 0);
        }
    }

    #pragma unroll
    for (int ti = 0; ti < 4; ++ti)
        #pragma unroll
        for (int reg = 0; reg < 4; ++reg) {
            int gm = bm0 + wm + ti * 16 + quad * 4 + reg;
            if (gm >= N_NODES) continue;
            #pragma unroll
            for (int tj = 0; tj < 4; ++tj) {
                int col = wn + tj * 16 + lrow;
                size_t idx = (size_t)gm * 128 + col;
                float v = fmaxf(accr[ti][tj][reg] + acc[idx], 0.f);
                if (!final_out) hout[idx] = f2bf(v);
                else if (fl)    ((u16*)fout)[idx] = f2bf(v);
                else            ((float*)fout)[idx] = v;
            }
        }
}

// ---------- pair GEMM (K=256, fallback): acc = or += agg2 @ Wstack slice ----------
__global__ __launch_bounds__(256, 2) void k_gemm_pair(
        const u16* __restrict__ A,      // [N,256]
        const u16* __restrict__ B,      // Wstack + l*131072 + p*256, row stride 1024
        float* __restrict__ acc, int first) {
    __shared__ u16 As[128 * 128];
    __shared__ u16 Bs[128 * 128];
    int tid = threadIdx.x;
    int bm0 = blockIdx.x * 128;
    int wave = tid >> 6, lane = tid & 63;
    int wm = (wave & 1) * 64, wn = (wave >> 1) * 64;
    int lrow = lane & 15, quad = lane >> 4;

    v4f accr[4][4];
    #pragma unroll
    for (int i = 0; i < 4; ++i)
        #pragma unroll
        for (int j = 0; j < 4; ++j) accr[i][j] = (v4f){0.f, 0.f, 0.f, 0.f};

    for (int half = 0; half < 2; ++half) {
        if (half) __syncthreads();
        #pragma unroll
        for (int it = 0; it < 8; ++it) {
            int c = it * 256 + tid;
            int row = c >> 4, cc = c & 15, swz = cc ^ (row & 15);
            int grow = bm0 + row;
            int4 va = make_int4(0, 0, 0, 0);
            if (grow < N_NODES) va = *(const int4*)(A + (size_t)grow * 256 + half * 128 + cc * 8);
            *(int4*)(As + row * 128 + swz * 8) = va;
            int4 vb = *(const int4*)(B + (size_t)row * 1024 + half * 128 + cc * 8);
            *(int4*)(Bs + row * 128 + swz * 8) = vb;
        }
        __syncthreads();

        #pragma unroll
        for (int kk = 0; kk < 4; ++kk) {
            int chunk = kk * 4 + quad;
            int sw = (chunk ^ lrow) * 8;
            v8s a[4], b[4];
            #pragma unroll
            for (int t = 0; t < 4; ++t) a[t] = *(const v8s*)(As + (wm + t * 16 + lrow) * 128 + sw);
            #pragma unroll
            for (int t = 0; t < 4; ++t) b[t] = *(const v8s*)(Bs + (wn + t * 16 + lrow) * 128 + sw);
            #pragma unroll
            for (int ti = 0; ti < 4; ++ti)
                #pragma unroll
                for (int tj = 0; tj < 4; ++tj)
                    accr[ti][tj] = __builtin_amdgcn_mfma_f32_16x16x32_bf16(a[ti], b[tj], accr[ti][tj], 0, 0, 0);
        }
    }

    #pragma unroll
    for (int ti = 0; ti < 4; ++ti)
        #pragma unroll
        for (int reg = 0; reg < 4; ++reg) {
            int gm = bm0 + wm + ti * 16 + quad * 4 + reg;
            if (gm >= N_NODES) continue;
            #pragma unroll
            for (int tj = 0; tj < 4; ++tj) {
                int col = wn + tj * 16 + lrow;
                size_t idx = (size_t)gm * 128 + col;
                float v = accr[ti][tj][reg];
                if (!first) v += acc[idx];
                acc[idx] = v;
            }
        }
}

// ---------- root GEMM (K=128) ----------
// mode 0: acc = gemm + bias (f32, no relu)            [big path, runs first]
// mode 1: h   = relu(gemm + acc + bias) bf16          [pair path, layer 1]
// mode 2: out = relu(gemm + acc + bias) flag-dtype    [pair path, layer 2]
__global__ __launch_bounds__(256, 2) void k_gemm_root(
        const u16* __restrict__ A, const u16* __restrict__ B,
        const u16* __restrict__ bias, float* __restrict__ acc,
        u16* __restrict__ hout, void* __restrict__ fout,
        int mode, const int* __restrict__ flag) {
    __shared__ u16 As[128 * 128];
    __shared__ u16 Bs[128 * 128];
    int tid = threadIdx.x;
    int bm0 = blockIdx.x * 128;
    int wave = tid >> 6, lane = tid & 63;
    int wm = (wave & 1) * 64, wn = (wave >> 1) * 64;
    int lrow = lane & 15, quad = lane >> 4;
    int fl = *flag;

    #pragma unroll
    for (int it = 0; it < 8; ++it) {
        int c = it * 256 + tid;
        int row = c >> 4, cc = c & 15, swz = cc ^ (row & 15);
        int grow = bm0 + row;
        int4 va = make_int4(0, 0, 0, 0);
        if (grow < N_NODES) va = *(const int4*)(A + (size_t)grow * 128 + cc * 8);
        *(int4*)(As + row * 128 + swz * 8) = va;
        int4 vb = *(const int4*)(B + (size_t)row * 128 + cc * 8);
        *(int4*)(Bs + row * 128 + swz * 8) = vb;
    }
    __syncthreads();

    v4f accr[4][4];
    #pragma unroll
    for (int i = 0; i < 4; ++i)
        #pragma unroll
        for (int j = 0; j < 4; ++j) accr[i][j] = (v4f){0.f, 0.f, 0.f, 0.f};

    #pragma unroll
    for (int kk = 0; kk < 4; ++kk) {
        int chunk = kk * 4 + quad;
        int sw = (chunk ^ lrow) * 8;
        v8s a[4], b[4];
        #pragma unroll
        for (int t = 0; t < 4; ++t) a[t] = *(const v8s*)(As + (wm + t * 16 + lrow) * 128 + sw);
        #pragma unroll
        for (int t = 0; t < 4; ++t) b[t] = *(const v8s*)(Bs + (wn + t * 16 + lrow) * 128 + sw);
        #pragma unroll
        for (int ti = 0; ti < 4; ++ti)
            #pragma unroll
            for (int tj = 0; tj < 4; ++tj)
                accr[ti][tj] = __builtin_amdgcn_mfma_f32_16x16x32_bf16(a[ti], b[tj], accr[ti][tj], 0, 0, 0);
    }

    #pragma unroll
    for (int ti = 0; ti < 4; ++ti)
        #pragma unroll
        for (int reg = 0; reg < 4; ++reg) {
            int gm = bm0 + wm + ti * 16 + quad * 4 + reg;
            if (gm >= N_NODES) continue;
            #pragma unroll
            for (int tj = 0; tj < 4; ++tj) {
                int col = wn + tj * 16 + lrow;
                size_t idx = (size_t)gm * 128 + col;
                float v = accr[ti][tj][reg];
                if (mode == 0) {
                    acc[idx] = v + bf2f(bias[col]);
                } else {
                    v = fmaxf(v + acc[idx] + bf2f(bias[col]), 0.f);
                    if (mode == 1)  hout[idx] = f2bf(v);
                    else if (fl)    ((u16*)fout)[idx] = f2bf(v);
                    else            ((float*)fout)[idx] = v;
                }
            }
        }
}

__global__ void k_relemb(const void* __restrict__ src, void* __restrict__ out,
                         const int* __restrict__ flag) {
    int i = blockIdx.x * 256 + threadIdx.x;
    if (i >= N_REL * 128) return;
    size_t o = (size_t)N_NODES * 128 + i;
    if (*flag) ((u16*)out)[o]   = ((const u16*)src)[i];
    else       ((float*)out)[o] = ((const float*)src)[i];
}

// ---------------- launch ----------------
static inline size_t align_up(size_t x, size_t a) { return (x + a - 1) & ~(a - 1); }

extern "C" void kernel_launch(void* const* d_in, const int* in_sizes, int n_in,
                              void* d_out, int out_size, void* d_ws, size_t ws_size,
                              hipStream_t stream) {
    const int* ei = (const int*)d_in[1];
    const int* et = (const int*)d_in[2];

    char* ws = (char*)d_ws;
    size_t off = 0;
    int* flag    = (int*)(ws + off);  off = align_up(off + 4, 256);
    u16* Wstack  = (u16*)(ws + off);  off = align_up(off + (size_t)2 * 128 * 1024 * 2, 256);
    u16* Wtr     = (u16*)(ws + off);  off = align_up(off + (size_t)2 * 128 * 128 * 2, 256);
    u16* bc      = (u16*)(ws + off);  off = align_up(off + 512, 256);
    u16* xc      = (u16*)(ws + off);  off = align_up(off + (size_t)N_NODES * 128 * 2, 256);
    int* deg     = (int*)(ws + off);  off += (size_t)N_NODES * 4;    // deg+cursor contiguous
    int* cursor  = (int*)(ws + off);  off = align_up(off + (size_t)N_NODES * 4, 256);
    int* rowptr  = (int*)(ws + off);  off = align_up(off + (size_t)(N_NODES + 1) * 4, 256);
    int* psum    = (int*)(ws + off);  off = align_up(off + (size_t)NB_SCAN * 4, 256);
    int* eval    = (int*)(ws + off);  off = align_up(off + (size_t)N_EDGES * 4, 256);
    float* acc   = (float*)(ws + off);off = align_up(off + (size_t)N_NODES * 128 * 4, 256);
    u16* h       = (u16*)(ws + off);  off = align_up(off + (size_t)N_NODES * 128 * 2, 256);
    u16* aggbuf  = (u16*)(ws + off);
    size_t need_big  = off + (size_t)N_NODES * 1024 * 2;   // ~157 MB
    int big = (ws_size >= need_big);
    (void)in_sizes; (void)n_in; (void)out_size;

    // dtype + conversions + weight prep
    k_detect<<<1, 256, 0, stream>>>((const u32*)d_in[0], flag);
    k_convert<<<(N_NODES * 128 + 255) / 256, 256, 0, stream>>>(d_in[0], xc, N_NODES * 128, flag);
    k_prep_w<<<1153, 256, 0, stream>>>(d_in[3], d_in[4], d_in[5], d_in[6], d_in[7], d_in[8],
                                       flag, Wstack, Wtr, bc);

    // graph prep
    k_zero_i32<<<(2 * N_NODES + 255) / 256, 256, 0, stream>>>(deg, 2 * N_NODES);
    k_count<<<(N_EDGES + 255) / 256, 256, 0, stream>>>(ei, deg);
    k_scan1<<<NB_SCAN, 256, 0, stream>>>(deg, rowptr, psum);
    k_scan2<<<1, 256, 0, stream>>>(psum);
    k_scan3<<<NB_SCAN, 256, 0, stream>>>(rowptr, psum);
    k_fill<<<(N_EDGES + 255) / 256, 256, 0, stream>>>(ei, et, rowptr, cursor, eval);

    int ngrid = (N_NODES + 127) / 128;
    if (big) {
        for (int l = 0; l < 2; ++l) {
            const u16* src = l ? h : xc;
            k_gemm_root<<<ngrid, 256, 0, stream>>>(src, Wtr + l * 16384, bc + l * 128,
                                                   acc, h, d_out, 0, flag);
            k_agg_all<<<(N_NODES + 3) / 4, 256, 0, stream>>>(src, rowptr, eval, aggbuf);
            k_gemm_big<<<ngrid, 256, 0, stream>>>(aggbuf, Wstack + l * 131072, acc,
                                                  h, d_out, l, flag);
        }
    } else {
        for (int l = 0; l < 2; ++l) {
            const u16* src = l ? h : xc;
            for (int p = 0; p < 4; ++p) {
                k_agg_pair<<<(N_NODES + 3) / 4, 256, 0, stream>>>(src, rowptr, eval, aggbuf, p);
                k_gemm_pair<<<ngrid, 256, 0, stream>>>(
                    aggbuf, Wstack + l * 131072 + p * 256, acc, p == 0 ? 1 : 0);
            }
            k_gemm_root<<<ngrid, 256, 0, stream>>>(src, Wtr + l * 16384, bc + l * 128,
                                                   acc, h, d_out, l + 1, flag);
        }
    }
    k_relemb<<<4, 256, 0, stream>>>(d_in[9], d_out, flag);
}

// Round 4
// 416.039 us; speedup vs baseline: 2.0518x; 1.0024x over previous
//
#include <hip/hip_runtime.h>
#include <stdint.h>

#define N_NODES 50000
#define N_EDGES 600000
#define N_REL   8
#define NB_SCAN ((N_NODES + 255) / 256)

typedef short v8s __attribute__((ext_vector_type(8)));
typedef float v4f __attribute__((ext_vector_type(4)));
typedef unsigned short u16;
typedef unsigned int   u32;

__device__ __forceinline__ float bf2f(u16 u) {
    union { u32 i; float f; } t; t.i = ((u32)u) << 16; return t.f;
}
__device__ __forceinline__ u16 f2bf(float f) {
    union { float f; u32 i; } t; t.f = f;
    u32 lsb = (t.i >> 16) & 1u;
    t.i += 0x7fffu + lsb;            // round-to-nearest-even
    return (u16)(t.i >> 16);
}
__device__ __forceinline__ float load_f(const void* p, int i, int fl) {
    return fl ? bf2f(((const u16*)p)[i]) : ((const float*)p)[i];
}

// ---------- dtype detection: bf16 vs f32 (bits[14:7] of low halfword = exponent if bf16) ----------
__global__ void k_detect(const u32* __restrict__ x, int* __restrict__ flag) {
    __shared__ int cnt;
    int tid = threadIdx.x;
    if (tid == 0) cnt = 0;
    __syncthreads();
    int local = 0;
    for (int j = 0; j < 4; ++j) {
        u32 e = (x[tid * 4 + j] >> 7) & 0xffu;
        if (e >= 112u && e < 144u) local++;
    }
    atomicAdd(&cnt, local);
    __syncthreads();
    if (tid == 0) *flag = (cnt >= 512) ? 1 : 0;   // 1 = bf16, 0 = f32
}

__global__ void k_convert(const void* __restrict__ src, u16* __restrict__ dst, int n,
                          const int* __restrict__ flag) {
    int i = blockIdx.x * 256 + threadIdx.x;
    if (i >= n) return;
    if (*flag) dst[i] = ((const u16*)src)[i];
    else       dst[i] = f2bf(((const float*)src)[i]);
}

// ---------- weight prep ----------
// Wstack[l][j][k] = W_l[k/128][k%128][j]  (k = r*128 + kk)
// Wtr[l][j][k]    = root_l[k][j]
// bc[l][i]        = bias_l[i]
__global__ void k_prep_w(const void* __restrict__ W1, const void* __restrict__ r1,
                         const void* __restrict__ b1, const void* __restrict__ W2,
                         const void* __restrict__ r2, const void* __restrict__ b2,
                         const int* __restrict__ flag,
                         u16* __restrict__ Wstack, u16* __restrict__ Wtr,
                         u16* __restrict__ bc) {
    int o = blockIdx.x * 256 + threadIdx.x;
    int fl = *flag;
    if (o < 262144) {
        int l = o >> 17, rem = o & 0x1ffff;
        int j = rem >> 10, k = rem & 1023;
        int r = k >> 7, kk = k & 127;
        const void* w = l ? W2 : W1;
        Wstack[o] = f2bf(load_f(w, r * 16384 + kk * 128 + j, fl));
    } else if (o < 262144 + 32768) {
        int o2 = o - 262144;
        int l = o2 >> 14, rem = o2 & 0x3fff;
        int j = rem >> 7, k = rem & 127;
        Wtr[o2] = f2bf(load_f(l ? r2 : r1, k * 128 + j, fl));
    } else if (o < 262144 + 32768 + 256) {
        int o2 = o - 262144 - 32768;
        bc[o2] = f2bf(load_f((o2 >> 7) ? b2 : b1, o2 & 127, fl));
    }
}

// ---------- graph prep ----------
__global__ void k_zero_i32(int* __restrict__ p, int n) {
    int i = blockIdx.x * 256 + threadIdx.x;
    if (i < n) p[i] = 0;
}

__global__ void k_count(const int* __restrict__ ei, int* __restrict__ deg) {
    int i = blockIdx.x * 256 + threadIdx.x;
    if (i >= N_EDGES) return;
    atomicAdd(&deg[ei[N_EDGES + i]], 1);
}

__global__ void k_scan1(const int* __restrict__ deg, int* __restrict__ rowptr,
                        int* __restrict__ psum) {
    __shared__ int lds[256];
    int tid = threadIdx.x;
    int idx = blockIdx.x * 256 + tid;
    int v = (idx < N_NODES) ? deg[idx] : 0;
    lds[tid] = v;
    __syncthreads();
    for (int off = 1; off < 256; off <<= 1) {
        int t = (tid >= off) ? lds[tid - off] : 0;
        __syncthreads();
        lds[tid] += t;
        __syncthreads();
    }
    if (idx < N_NODES) rowptr[idx + 1] = lds[tid];
    if (tid == 255) psum[blockIdx.x] = lds[255];
}

__global__ void k_scan2(int* __restrict__ psum) {
    __shared__ int lds[256];
    int tid = threadIdx.x;
    int v = (tid < NB_SCAN) ? psum[tid] : 0;
    lds[tid] = v;
    __syncthreads();
    for (int off = 1; off < 256; off <<= 1) {
        int t = (tid >= off) ? lds[tid - off] : 0;
        __syncthreads();
        lds[tid] += t;
        __syncthreads();
    }
    if (tid < NB_SCAN) psum[tid] = lds[tid] - v;   // exclusive
}

__global__ void k_scan3(int* __restrict__ rowptr, const int* __restrict__ psum) {
    int idx = blockIdx.x * 256 + threadIdx.x;
    if (idx < N_NODES) rowptr[idx + 1] += psum[blockIdx.x];
    if (idx == 0) rowptr[0] = 0;
}

__global__ void k_fill(const int* __restrict__ ei, const int* __restrict__ et,
                       const int* __restrict__ rowptr, int* __restrict__ cursor,
                       int* __restrict__ eval) {
    int i = blockIdx.x * 256 + threadIdx.x;
    if (i >= N_EDGES) return;
    int d = ei[N_EDGES + i];
    int pos = atomicAdd(&cursor[d], 1);
    eval[rowptr[d] + pos] = (ei[i] << 3) | et[i];
}

// ---------- per-relation transform GEMM: xw[r][m][n] = src @ W_r  (r==8: acc = src@root + bias) ----------
__global__ __launch_bounds__(256, 2) void k_gemm_xw(
        const u16* __restrict__ A,       // [N,128] bf16 (x or h)
        const u16* __restrict__ Wstack,  // [l][128][1024]
        const u16* __restrict__ Wtr,     // [l][128][128]
        const u16* __restrict__ bias,    // bc + l*128
        u16* __restrict__ xw,            // [8][N][128] bf16
        float* __restrict__ acc,         // [N,128] f32
        int layer) {
    __shared__ u16 As[128 * 128];
    __shared__ u16 Bs[128 * 128];
    int tid = threadIdx.x;
    int bm0 = blockIdx.x * 128;
    int r = blockIdx.y;
    const u16* B;
    int bstride;
    if (r < 8) { B = Wstack + layer * 131072 + r * 128; bstride = 1024; }
    else       { B = Wtr + layer * 16384;               bstride = 128;  }

    #pragma unroll
    for (int it = 0; it < 8; ++it) {
        int c = it * 256 + tid;
        int row = c >> 4, cc = c & 15, swz = cc ^ (row & 15);
        int grow = bm0 + row;
        int4 va = make_int4(0, 0, 0, 0);
        if (grow < N_NODES) va = *(const int4*)(A + (size_t)grow * 128 + cc * 8);
        *(int4*)(As + row * 128 + swz * 8) = va;
        int4 vb = *(const int4*)(B + (size_t)row * bstride + cc * 8);
        *(int4*)(Bs + row * 128 + swz * 8) = vb;
    }
    __syncthreads();

    int wave = tid >> 6, lane = tid & 63;
    int wm = (wave & 1) * 64, wn = (wave >> 1) * 64;
    int lrow = lane & 15, quad = lane >> 4;

    v4f accr[4][4];
    #pragma unroll
    for (int i = 0; i < 4; ++i)
        #pragma unroll
        for (int j = 0; j < 4; ++j) accr[i][j] = (v4f){0.f, 0.f, 0.f, 0.f};

    #pragma unroll
    for (int kk = 0; kk < 4; ++kk) {
        int chunk = kk * 4 + quad;
        int sw = (chunk ^ lrow) * 8;
        v8s a[4], b[4];
        #pragma unroll
        for (int t = 0; t < 4; ++t) a[t] = *(const v8s*)(As + (wm + t * 16 + lrow) * 128 + sw);
        #pragma unroll
        for (int t = 0; t < 4; ++t) b[t] = *(const v8s*)(Bs + (wn + t * 16 + lrow) * 128 + sw);
        #pragma unroll
        for (int ti = 0; ti < 4; ++ti)
            #pragma unroll
            for (int tj = 0; tj < 4; ++tj)
                accr[ti][tj] = __builtin_amdgcn_mfma_f32_16x16x32_bf16(a[ti], b[tj], accr[ti][tj], 0, 0, 0);
    }

    #pragma unroll
    for (int ti = 0; ti < 4; ++ti)
        #pragma unroll
        for (int reg = 0; reg < 4; ++reg) {
            int gm = bm0 + wm + ti * 16 + quad * 4 + reg;
            if (gm >= N_NODES) continue;
            #pragma unroll
            for (int tj = 0; tj < 4; ++tj) {
                int col = wn + tj * 16 + lrow;
                float v = accr[ti][tj][reg];
                if (r < 8) xw[((size_t)r * N_NODES + gm) * 128 + col] = f2bf(v);
                else       acc[(size_t)gm * 128 + col] = v + bf2f(bias[col]);
            }
        }
}

// ---------- fused gather-mean + root + relu: one wave per node, single pass ----------
#define ACC_EDGE(EV, UX, UY) do {                                          \
    int r_ = (EV) & 7; float fx_ = bf2f(UX), fy_ = bf2f(UY);               \
    switch (r_) {                                                          \
    case 0: s0x += fx_; s0y += fy_; c0++; break;                           \
    case 1: s1x += fx_; s1y += fy_; c1++; break;                           \
    case 2: s2x += fx_; s2y += fy_; c2_++; break;                          \
    case 3: s3x += fx_; s3y += fy_; c3++; break;                           \
    case 4: s4x += fx_; s4y += fy_; c4++; break;                           \
    case 5: s5x += fx_; s5y += fy_; c5++; break;                           \
    case 6: s6x += fx_; s6y += fy_; c6++; break;                           \
    default: s7x += fx_; s7y += fy_; c7++; break;                          \
    } } while (0)

__global__ __launch_bounds__(256) void k_agg_out(
        const float* __restrict__ acc,   // [N,128] f32 (root + bias)
        const u16* __restrict__ xw,      // [8][N][128] bf16
        const int* __restrict__ rowptr, const int* __restrict__ eval,
        u16* __restrict__ hout, void* __restrict__ fout,
        int final_out, const int* __restrict__ flag) {
    int wave = threadIdx.x >> 6, lane = threadIdx.x & 63;
    int node = blockIdx.x * 4 + wave;
    if (node >= N_NODES) return;
    int c2 = lane * 2;
    float s0x=0,s0y=0,s1x=0,s1y=0,s2x=0,s2y=0,s3x=0,s3y=0;
    float s4x=0,s4y=0,s5x=0,s5y=0,s6x=0,s6y=0,s7x=0,s7y=0;
    int c0=0,c1=0,c2_=0,c3=0,c4=0,c5=0,c6=0,c7=0;
    int s = rowptr[node], e = rowptr[node + 1];
    int i = s;
    for (; i + 1 < e; i += 2) {
        int ev0 = eval[i], ev1 = eval[i + 1];
        ushort2 u0 = *(const ushort2*)(xw + (((size_t)(ev0 & 7) * N_NODES + (ev0 >> 3)) << 7) + c2);
        ushort2 u1 = *(const ushort2*)(xw + (((size_t)(ev1 & 7) * N_NODES + (ev1 >> 3)) << 7) + c2);
        ACC_EDGE(ev0, u0.x, u0.y);
        ACC_EDGE(ev1, u1.x, u1.y);
    }
    if (i < e) {
        int ev0 = eval[i];
        ushort2 u0 = *(const ushort2*)(xw + (((size_t)(ev0 & 7) * N_NODES + (ev0 >> 3)) << 7) + c2);
        ACC_EDGE(ev0, u0.x, u0.y);
    }
    const float* ar = acc + (size_t)node * 128 + c2;
    float ox = ar[0], oy = ar[1];
    float inv;
    inv = 1.f / (float)(c0 > 0 ? c0 : 1); ox += s0x * inv; oy += s0y * inv;
    inv = 1.f / (float)(c1 > 0 ? c1 : 1); ox += s1x * inv; oy += s1y * inv;
    inv = 1.f / (float)(c2_> 0 ? c2_: 1); ox += s2x * inv; oy += s2y * inv;
    inv = 1.f / (float)(c3 > 0 ? c3 : 1); ox += s3x * inv; oy += s3y * inv;
    inv = 1.f / (float)(c4 > 0 ? c4 : 1); ox += s4x * inv; oy += s4y * inv;
    inv = 1.f / (float)(c5 > 0 ? c5 : 1); ox += s5x * inv; oy += s5y * inv;
    inv = 1.f / (float)(c6 > 0 ? c6 : 1); ox += s6x * inv; oy += s6y * inv;
    inv = 1.f / (float)(c7 > 0 ? c7 : 1); ox += s7x * inv; oy += s7y * inv;
    ox = fmaxf(ox, 0.f);
    oy = fmaxf(oy, 0.f);
    size_t idx = (size_t)node * 128 + c2;
    if (!final_out) {
        ushort2 o; o.x = f2bf(ox); o.y = f2bf(oy);
        *(ushort2*)(hout + idx) = o;
    } else if (*flag) {
        ushort2 o; o.x = f2bf(ox); o.y = f2bf(oy);
        *(ushort2*)((u16*)fout + idx) = o;
    } else {
        float2 o; o.x = ox; o.y = oy;
        *(float2*)((float*)fout + idx) = o;
    }
}

// ---------- fallback path (small workspace): pair aggregation + K=256 GEMMs ----------
__global__ __launch_bounds__(256) void k_agg_pair(
        const u16* __restrict__ feat, const int* __restrict__ rowptr,
        const int* __restrict__ eval, u16* __restrict__ agg2, int p) {
    int wave = threadIdx.x >> 6, lane = threadIdx.x & 63;
    int node = blockIdx.x * 4 + wave;
    if (node >= N_NODES) return;
    int c2 = lane * 2;
    float a0x = 0.f, a0y = 0.f, a1x = 0.f, a1y = 0.f;
    int c0 = 0, c1 = 0;
    int s = rowptr[node], e = rowptr[node + 1];
    for (int i = s; i < e; ++i) {
        int ev = eval[i];
        int r = ev & 7;
        if ((r >> 1) != p) continue;
        ushort2 u = *(const ushort2*)(feat + ((ev >> 3) << 7) + c2);
        if (r & 1) { a1x += bf2f(u.x); a1y += bf2f(u.y); c1++; }
        else       { a0x += bf2f(u.x); a0y += bf2f(u.y); c0++; }
    }
    float i0 = 1.f / (float)(c0 > 0 ? c0 : 1);
    float i1 = 1.f / (float)(c1 > 0 ? c1 : 1);
    u16* d0 = agg2 + node * 256 + c2;
    ushort2 o0; o0.x = f2bf(a0x * i0); o0.y = f2bf(a0y * i0);
    ushort2 o1; o1.x = f2bf(a1x * i1); o1.y = f2bf(a1y * i1);
    *(ushort2*)d0 = o0;
    *(ushort2*)(d0 + 128) = o1;
}

__global__ __launch_bounds__(256, 2) void k_gemm_pair(
        const u16* __restrict__ A, const u16* __restrict__ B,
        float* __restrict__ acc, int first) {
    __shared__ u16 As[128 * 128];
    __shared__ u16 Bs[128 * 128];
    int tid = threadIdx.x;
    int bm0 = blockIdx.x * 128;
    int wave = tid >> 6, lane = tid & 63;
    int wm = (wave & 1) * 64, wn = (wave >> 1) * 64;
    int lrow = lane & 15, quad = lane >> 4;

    v4f accr[4][4];
    #pragma unroll
    for (int i = 0; i < 4; ++i)
        #pragma unroll
        for (int j = 0; j < 4; ++j) accr[i][j] = (v4f){0.f, 0.f, 0.f, 0.f};

    for (int half = 0; half < 2; ++half) {
        if (half) __syncthreads();
        #pragma unroll
        for (int it = 0; it < 8; ++it) {
            int c = it * 256 + tid;
            int row = c >> 4, cc = c & 15, swz = cc ^ (row & 15);
            int grow = bm0 + row;
            int4 va = make_int4(0, 0, 0, 0);
            if (grow < N_NODES) va = *(const int4*)(A + (size_t)grow * 256 + half * 128 + cc * 8);
            *(int4*)(As + row * 128 + swz * 8) = va;
            int4 vb = *(const int4*)(B + (size_t)row * 1024 + half * 128 + cc * 8);
            *(int4*)(Bs + row * 128 + swz * 8) = vb;
        }
        __syncthreads();

        #pragma unroll
        for (int kk = 0; kk < 4; ++kk) {
            int chunk = kk * 4 + quad;
            int sw = (chunk ^ lrow) * 8;
            v8s a[4], b[4];
            #pragma unroll
            for (int t = 0; t < 4; ++t) a[t] = *(const v8s*)(As + (wm + t * 16 + lrow) * 128 + sw);
            #pragma unroll
            for (int t = 0; t < 4; ++t) b[t] = *(const v8s*)(Bs + (wn + t * 16 + lrow) * 128 + sw);
            #pragma unroll
            for (int ti = 0; ti < 4; ++ti)
                #pragma unroll
                for (int tj = 0; tj < 4; ++tj)
                    accr[ti][tj] = __builtin_amdgcn_mfma_f32_16x16x32_bf16(a[ti], b[tj], accr[ti][tj], 0, 0, 0);
        }
    }

    #pragma unroll
    for (int ti = 0; ti < 4; ++ti)
        #pragma unroll
        for (int reg = 0; reg < 4; ++reg) {
            int gm = bm0 + wm + ti * 16 + quad * 4 + reg;
            if (gm >= N_NODES) continue;
            #pragma unroll
            for (int tj = 0; tj < 4; ++tj) {
                int col = wn + tj * 16 + lrow;
                size_t idx = (size_t)gm * 128 + col;
                float v = accr[ti][tj][reg];
                if (!first) v += acc[idx];
                acc[idx] = v;
            }
        }
}

// mode 1: h = relu(gemm + acc + bias) bf16; mode 2: out = relu(...) flag-dtype
__global__ __launch_bounds__(256, 2) void k_gemm_root(
        const u16* __restrict__ A, const u16* __restrict__ B,
        const u16* __restrict__ bias, float* __restrict__ acc,
        u16* __restrict__ hout, void* __restrict__ fout,
        int mode, const int* __restrict__ flag) {
    __shared__ u16 As[128 * 128];
    __shared__ u16 Bs[128 * 128];
    int tid = threadIdx.x;
    int bm0 = blockIdx.x * 128;
    int wave = tid >> 6, lane = tid & 63;
    int wm = (wave & 1) * 64, wn = (wave >> 1) * 64;
    int lrow = lane & 15, quad = lane >> 4;
    int fl = *flag;

    #pragma unroll
    for (int it = 0; it < 8; ++it) {
        int c = it * 256 + tid;
        int row = c >> 4, cc = c & 15, swz = cc ^ (row & 15);
        int grow = bm0 + row;
        int4 va = make_int4(0, 0, 0, 0);
        if (grow < N_NODES) va = *(const int4*)(A + (size_t)grow * 128 + cc * 8);
        *(int4*)(As + row * 128 + swz * 8) = va;
        int4 vb = *(const int4*)(B + (size_t)row * 128 + cc * 8);
        *(int4*)(Bs + row * 128 + swz * 8) = vb;
    }
    __syncthreads();

    v4f accr[4][4];
    #pragma unroll
    for (int i = 0; i < 4; ++i)
        #pragma unroll
        for (int j = 0; j < 4; ++j) accr[i][j] = (v4f){0.f, 0.f, 0.f, 0.f};

    #pragma unroll
    for (int kk = 0; kk < 4; ++kk) {
        int chunk = kk * 4 + quad;
        int sw = (chunk ^ lrow) * 8;
        v8s a[4], b[4];
        #pragma unroll
        for (int t = 0; t < 4; ++t) a[t] = *(const v8s*)(As + (wm + t * 16 + lrow) * 128 + sw);
        #pragma unroll
        for (int t = 0; t < 4; ++t) b[t] = *(const v8s*)(Bs + (wn + t * 16 + lrow) * 128 + sw);
        #pragma unroll
        for (int ti = 0; ti < 4; ++ti)
            #pragma unroll
            for (int tj = 0; tj < 4; ++tj)
                accr[ti][tj] = __builtin_amdgcn_mfma_f32_16x16x32_bf16(a[ti], b[tj], accr[ti][tj], 0, 0, 0);
    }

    #pragma unroll
    for (int ti = 0; ti < 4; ++ti)
        #pragma unroll
        for (int reg = 0; reg < 4; ++reg) {
            int gm = bm0 + wm + ti * 16 + quad * 4 + reg;
            if (gm >= N_NODES) continue;
            #pragma unroll
            for (int tj = 0; tj < 4; ++tj) {
                int col = wn + tj * 16 + lrow;
                size_t idx = (size_t)gm * 128 + col;
                float v = fmaxf(accr[ti][tj][reg] + acc[idx] + bf2f(bias[col]), 0.f);
                if (mode == 1)  hout[idx] = f2bf(v);
                else if (fl)    ((u16*)fout)[idx] = f2bf(v);
                else            ((float*)fout)[idx] = v;
            }
        }
}

__global__ void k_relemb(const void* __restrict__ src, void* __restrict__ out,
                         const int* __restrict__ flag) {
    int i = blockIdx.x * 256 + threadIdx.x;
    if (i >= N_REL * 128) return;
    size_t o = (size_t)N_NODES * 128 + i;
    if (*flag) ((u16*)out)[o]   = ((const u16*)src)[i];
    else       ((float*)out)[o] = ((const float*)src)[i];
}

// ---------------- launch ----------------
static inline size_t align_up(size_t x, size_t a) { return (x + a - 1) & ~(a - 1); }

extern "C" void kernel_launch(void* const* d_in, const int* in_sizes, int n_in,
                              void* d_out, int out_size, void* d_ws, size_t ws_size,
                              hipStream_t stream) {
    const int* ei = (const int*)d_in[1];
    const int* et = (const int*)d_in[2];

    char* ws = (char*)d_ws;
    size_t off = 0;
    int* flag    = (int*)(ws + off);  off = align_up(off + 4, 256);
    u16* Wstack  = (u16*)(ws + off);  off = align_up(off + (size_t)2 * 128 * 1024 * 2, 256);
    u16* Wtr     = (u16*)(ws + off);  off = align_up(off + (size_t)2 * 128 * 128 * 2, 256);
    u16* bc      = (u16*)(ws + off);  off = align_up(off + 512, 256);
    u16* xc      = (u16*)(ws + off);  off = align_up(off + (size_t)N_NODES * 128 * 2, 256);
    int* deg     = (int*)(ws + off);  off += (size_t)N_NODES * 4;    // deg+cursor contiguous
    int* cursor  = (int*)(ws + off);  off = align_up(off + (size_t)N_NODES * 4, 256);
    int* rowptr  = (int*)(ws + off);  off = align_up(off + (size_t)(N_NODES + 1) * 4, 256);
    int* psum    = (int*)(ws + off);  off = align_up(off + (size_t)NB_SCAN * 4, 256);
    int* eval    = (int*)(ws + off);  off = align_up(off + (size_t)N_EDGES * 4, 256);
    float* acc   = (float*)(ws + off);off = align_up(off + (size_t)N_NODES * 128 * 4, 256);
    u16* h       = (u16*)(ws + off);  off = align_up(off + (size_t)N_NODES * 128 * 2, 256);
    u16* xw      = (u16*)(ws + off);                 // [8][N][128] big path / agg2 fallback
    size_t need_big = off + (size_t)N_REL * N_NODES * 128 * 2;   // ~157 MB
    int big = (ws_size >= need_big);
    (void)in_sizes; (void)n_in; (void)out_size;

    // dtype + conversions + weight prep
    k_detect<<<1, 256, 0, stream>>>((const u32*)d_in[0], flag);
    k_convert<<<(N_NODES * 128 + 255) / 256, 256, 0, stream>>>(d_in[0], xc, N_NODES * 128, flag);
    k_prep_w<<<1153, 256, 0, stream>>>(d_in[3], d_in[4], d_in[5], d_in[6], d_in[7], d_in[8],
                                       flag, Wstack, Wtr, bc);

    // graph prep
    k_zero_i32<<<(2 * N_NODES + 255) / 256, 256, 0, stream>>>(deg, 2 * N_NODES);
    k_count<<<(N_EDGES + 255) / 256, 256, 0, stream>>>(ei, deg);
    k_scan1<<<NB_SCAN, 256, 0, stream>>>(deg, rowptr, psum);
    k_scan2<<<1, 256, 0, stream>>>(psum);
    k_scan3<<<NB_SCAN, 256, 0, stream>>>(rowptr, psum);
    k_fill<<<(N_EDGES + 255) / 256, 256, 0, stream>>>(ei, et, rowptr, cursor, eval);

    int ngrid = (N_NODES + 127) / 128;
    if (big) {
        dim3 ggrid(ngrid, 9);
        for (int l = 0; l < 2; ++l) {
            const u16* src = l ? h : xc;
            k_gemm_xw<<<ggrid, 256, 0, stream>>>(src, Wstack, Wtr, bc + l * 128, xw, acc, l);
            k_agg_out<<<(N_NODES + 3) / 4, 256, 0, stream>>>(acc, xw, rowptr, eval,
                                                             h, d_out, l, flag);
        }
    } else {
        for (int l = 0; l < 2; ++l) {
            const u16* src = l ? h : xc;
            for (int p = 0; p < 4; ++p) {
                k_agg_pair<<<(N_NODES + 3) / 4, 256, 0, stream>>>(src, rowptr, eval, xw, p);
                k_gemm_pair<<<ngrid, 256, 0, stream>>>(
                    xw, Wstack + l * 131072 + p * 256, acc, p == 0 ? 1 : 0);
            }
            k_gemm_root<<<ngrid, 256, 0, stream>>>(src, Wtr + l * 16384, bc + l * 128,
                                                   acc, h, d_out, l + 1, flag);
        }
    }
    k_relemb<<<4, 256, 0, stream>>>(d_in[9], d_out, flag);
}

// Round 5
// 371.041 us; speedup vs baseline: 2.3006x; 1.1213x over previous
//
#include <hip/hip_runtime.h>
#include <stdint.h>

#define N_NODES 50000
#define N_EDGES 600000
#define N_REL   8
#define KDIM    1152                      // 8 relations * 128 + 128 (root/self)
#define NB_SCAN ((N_NODES + 255) / 256)

typedef short v8s __attribute__((ext_vector_type(8)));
typedef float v4f __attribute__((ext_vector_type(4)));
typedef unsigned short u16;
typedef unsigned int   u32;

__device__ __forceinline__ float bf2f(u16 u) {
    union { u32 i; float f; } t; t.i = ((u32)u) << 16; return t.f;
}
__device__ __forceinline__ u16 f2bf(float f) {
    union { float f; u32 i; } t; t.f = f;
    u32 lsb = (t.i >> 16) & 1u;
    t.i += 0x7fffu + lsb;            // round-to-nearest-even
    return (u16)(t.i >> 16);
}
__device__ __forceinline__ float load_f(const void* p, int i, int fl) {
    return fl ? bf2f(((const u16*)p)[i]) : ((const float*)p)[i];
}

// ---------- dtype detection: bf16 vs f32 (bits[14:7] of low halfword = exponent if bf16) ----------
__global__ void k_detect(const u32* __restrict__ x, int* __restrict__ flag) {
    __shared__ int cnt;
    int tid = threadIdx.x;
    if (tid == 0) cnt = 0;
    __syncthreads();
    int local = 0;
    for (int j = 0; j < 4; ++j) {
        u32 e = (x[tid * 4 + j] >> 7) & 0xffu;
        if (e >= 112u && e < 144u) local++;
    }
    atomicAdd(&cnt, local);
    __syncthreads();
    if (tid == 0) *flag = (cnt >= 512) ? 1 : 0;   // 1 = bf16, 0 = f32
}

// ---------- weight prep ----------
// Wbig[l][j][k]: k in [0,1024) -> W_l[k/128][k%128][j]; k in [1024,1152) -> root_l[k-1024][j]
// bc[l][i] = bias_l[i]
__global__ void k_prep_w(const void* __restrict__ W1, const void* __restrict__ r1,
                         const void* __restrict__ b1, const void* __restrict__ W2,
                         const void* __restrict__ r2, const void* __restrict__ b2,
                         const int* __restrict__ flag,
                         u16* __restrict__ Wbig, u16* __restrict__ bc) {
    int o = blockIdx.x * 256 + threadIdx.x;
    int fl = *flag;
    if (o < 2 * 128 * KDIM) {
        int l = o / (128 * KDIM);
        int rem = o - l * (128 * KDIM);
        int j = rem / KDIM, k = rem - j * KDIM;
        float v;
        if (k < 1024) {
            int r = k >> 7, kk = k & 127;
            v = load_f(l ? W2 : W1, r * 16384 + kk * 128 + j, fl);
        } else {
            v = load_f(l ? r2 : r1, (k - 1024) * 128 + j, fl);
        }
        Wbig[o] = f2bf(v);
    } else if (o < 2 * 128 * KDIM + 256) {
        int o2 = o - 2 * 128 * KDIM;
        bc[o2] = f2bf(load_f((o2 >> 7) ? b2 : b1, o2 & 127, fl));
    }
}

// ---------- graph prep ----------
__global__ void k_zero_i32(int* __restrict__ p, int n) {
    int i = blockIdx.x * 256 + threadIdx.x;
    if (i < n) p[i] = 0;
}

__global__ void k_count(const int* __restrict__ ei, int* __restrict__ deg) {
    int i = blockIdx.x * 256 + threadIdx.x;
    if (i >= N_EDGES) return;
    atomicAdd(&deg[ei[N_EDGES + i]], 1);
}

__global__ void k_scan1(const int* __restrict__ deg, int* __restrict__ rowptr,
                        int* __restrict__ psum) {
    __shared__ int lds[256];
    int tid = threadIdx.x;
    int idx = blockIdx.x * 256 + tid;
    int v = (idx < N_NODES) ? deg[idx] : 0;
    lds[tid] = v;
    __syncthreads();
    for (int off = 1; off < 256; off <<= 1) {
        int t = (tid >= off) ? lds[tid - off] : 0;
        __syncthreads();
        lds[tid] += t;
        __syncthreads();
    }
    if (idx < N_NODES) rowptr[idx + 1] = lds[tid];
    if (tid == 255) psum[blockIdx.x] = lds[255];
}

__global__ void k_scan2(int* __restrict__ psum) {
    __shared__ int lds[256];
    int tid = threadIdx.x;
    int v = (tid < NB_SCAN) ? psum[tid] : 0;
    lds[tid] = v;
    __syncthreads();
    for (int off = 1; off < 256; off <<= 1) {
        int t = (tid >= off) ? lds[tid - off] : 0;
        __syncthreads();
        lds[tid] += t;
        __syncthreads();
    }
    if (tid < NB_SCAN) psum[tid] = lds[tid] - v;   // exclusive
}

__global__ void k_scan3(int* __restrict__ rowptr, const int* __restrict__ psum) {
    int idx = blockIdx.x * 256 + threadIdx.x;
    if (idx < N_NODES) rowptr[idx + 1] += psum[blockIdx.x];
    if (idx == 0) rowptr[0] = 0;
}

__global__ void k_fill(const int* __restrict__ ei, const int* __restrict__ et,
                       const int* __restrict__ rowptr, int* __restrict__ cursor,
                       int* __restrict__ eval) {
    int i = blockIdx.x * 256 + threadIdx.x;
    if (i >= N_EDGES) return;
    int d = ei[N_EDGES + i];
    int pos = atomicAdd(&cursor[d], 1);
    eval[rowptr[d] + pos] = (ei[i] << 3) | et[i];
}

// ---------- aggregation: 8 relation means + self slice -> aggAll[N,1152] ----------
#define ACC_EDGE(EV, FX, FY) do {                                          \
    int r_ = (EV) & 7;                                                     \
    switch (r_) {                                                          \
    case 0: s0x += (FX); s0y += (FY); c0++; break;                         \
    case 1: s1x += (FX); s1y += (FY); c1++; break;                         \
    case 2: s2x += (FX); s2y += (FY); c2_++; break;                        \
    case 3: s3x += (FX); s3y += (FY); c3++; break;                         \
    case 4: s4x += (FX); s4y += (FY); c4++; break;                         \
    case 5: s5x += (FX); s5y += (FY); c5++; break;                         \
    case 6: s6x += (FX); s6y += (FY); c6++; break;                         \
    default: s7x += (FX); s7y += (FY); c7++; break;                        \
    } } while (0)

__global__ __launch_bounds__(256) void k_agg_all(
        const void* __restrict__ feat,   // layer0: raw x (flag dtype); layer1: h (bf16)
        const int* __restrict__ rowptr, const int* __restrict__ eval,
        u16* __restrict__ aggAll, int layer, const int* __restrict__ flag) {
    int wave = threadIdx.x >> 6, lane = threadIdx.x & 63;
    int node = blockIdx.x * 4 + wave;
    if (node >= N_NODES) return;
    int c2 = lane * 2;
    int bf = layer ? 1 : *flag;
    float s0x=0,s0y=0,s1x=0,s1y=0,s2x=0,s2y=0,s3x=0,s3y=0;
    float s4x=0,s4y=0,s5x=0,s5y=0,s6x=0,s6y=0,s7x=0,s7y=0;
    int c0=0,c1=0,c2_=0,c3=0,c4=0,c5=0,c6=0,c7=0;
    int s = rowptr[node], e = rowptr[node + 1];
    float sfx, sfy;                       // self slice
    if (bf) {
        const u16* f = (const u16*)feat;
        int i = s;
        for (; i + 3 < e; i += 4) {
            int ev0 = eval[i], ev1 = eval[i+1], ev2 = eval[i+2], ev3 = eval[i+3];
            ushort2 u0 = *(const ushort2*)(f + ((ev0 >> 3) << 7) + c2);
            ushort2 u1 = *(const ushort2*)(f + ((ev1 >> 3) << 7) + c2);
            ushort2 u2 = *(const ushort2*)(f + ((ev2 >> 3) << 7) + c2);
            ushort2 u3 = *(const ushort2*)(f + ((ev3 >> 3) << 7) + c2);
            ACC_EDGE(ev0, bf2f(u0.x), bf2f(u0.y));
            ACC_EDGE(ev1, bf2f(u1.x), bf2f(u1.y));
            ACC_EDGE(ev2, bf2f(u2.x), bf2f(u2.y));
            ACC_EDGE(ev3, bf2f(u3.x), bf2f(u3.y));
        }
        for (; i < e; ++i) {
            int ev0 = eval[i];
            ushort2 u0 = *(const ushort2*)(f + ((ev0 >> 3) << 7) + c2);
            ACC_EDGE(ev0, bf2f(u0.x), bf2f(u0.y));
        }
        ushort2 su = *(const ushort2*)(f + ((size_t)node << 7) + c2);
        sfx = bf2f(su.x); sfy = bf2f(su.y);
    } else {
        const float* f = (const float*)feat;
        int i = s;
        for (; i + 3 < e; i += 4) {
            int ev0 = eval[i], ev1 = eval[i+1], ev2 = eval[i+2], ev3 = eval[i+3];
            float2 u0 = *(const float2*)(f + ((ev0 >> 3) << 7) + c2);
            float2 u1 = *(const float2*)(f + ((ev1 >> 3) << 7) + c2);
            float2 u2 = *(const float2*)(f + ((ev2 >> 3) << 7) + c2);
            float2 u3 = *(const float2*)(f + ((ev3 >> 3) << 7) + c2);
            ACC_EDGE(ev0, u0.x, u0.y);
            ACC_EDGE(ev1, u1.x, u1.y);
            ACC_EDGE(ev2, u2.x, u2.y);
            ACC_EDGE(ev3, u3.x, u3.y);
        }
        for (; i < e; ++i) {
            int ev0 = eval[i];
            float2 u0 = *(const float2*)(f + ((ev0 >> 3) << 7) + c2);
            ACC_EDGE(ev0, u0.x, u0.y);
        }
        float2 su = *(const float2*)(f + ((size_t)node << 7) + c2);
        sfx = su.x; sfy = su.y;
    }
    u16* d = aggAll + (size_t)node * KDIM + c2;
    float inv; ushort2 o;
    inv = 1.f / (float)(c0 > 0 ? c0 : 1); o.x = f2bf(s0x*inv); o.y = f2bf(s0y*inv); *(ushort2*)(d)        = o;
    inv = 1.f / (float)(c1 > 0 ? c1 : 1); o.x = f2bf(s1x*inv); o.y = f2bf(s1y*inv); *(ushort2*)(d + 128)  = o;
    inv = 1.f / (float)(c2_> 0 ? c2_: 1); o.x = f2bf(s2x*inv); o.y = f2bf(s2y*inv); *(ushort2*)(d + 256)  = o;
    inv = 1.f / (float)(c3 > 0 ? c3 : 1); o.x = f2bf(s3x*inv); o.y = f2bf(s3y*inv); *(ushort2*)(d + 384)  = o;
    inv = 1.f / (float)(c4 > 0 ? c4 : 1); o.x = f2bf(s4x*inv); o.y = f2bf(s4y*inv); *(ushort2*)(d + 512)  = o;
    inv = 1.f / (float)(c5 > 0 ? c5 : 1); o.x = f2bf(s5x*inv); o.y = f2bf(s5y*inv); *(ushort2*)(d + 640)  = o;
    inv = 1.f / (float)(c6 > 0 ? c6 : 1); o.x = f2bf(s6x*inv); o.y = f2bf(s6y*inv); *(ushort2*)(d + 768)  = o;
    inv = 1.f / (float)(c7 > 0 ? c7 : 1); o.x = f2bf(s7x*inv); o.y = f2bf(s7y*inv); *(ushort2*)(d + 896)  = o;
    o.x = f2bf(sfx); o.y = f2bf(sfy);                                              *(ushort2*)(d + 1024) = o;
}

// ---------- fused GEMM (K=1152): out = relu(aggAll @ Wbig[l] + bias) ----------
// BM=64 tile: LDS 48 KB -> 3 blocks/CU; grid 782 -> ~3 deep on 256 CUs.
__global__ __launch_bounds__(256, 3) void k_gemm_fused(
        const u16* __restrict__ A,      // [N,1152] bf16
        const u16* __restrict__ B,      // [128][1152] bf16 (n-major, k contiguous)
        const u16* __restrict__ bias,   // [128]
        u16* __restrict__ hout, void* __restrict__ fout,
        int final_out, const int* __restrict__ flag) {
    __shared__ u16 As[64 * 128];        // 16 KB
    __shared__ u16 Bs[128 * 128];       // 32 KB
    int tid = threadIdx.x;
    int bm0 = blockIdx.x * 64;
    int wave = tid >> 6, lane = tid & 63;
    int wm = (wave & 1) * 32, wn = (wave >> 1) * 64;
    int lrow = lane & 15, quad = lane >> 4;

    v4f accr[2][4];
    #pragma unroll
    for (int i = 0; i < 2; ++i)
        #pragma unroll
        for (int j = 0; j < 4; ++j) accr[i][j] = (v4f){0.f, 0.f, 0.f, 0.f};

    for (int h = 0; h < 9; ++h) {
        if (h) __syncthreads();
        // stage A half: 64x128 bf16 = 1024 int4 (4/thread)
        #pragma unroll
        for (int it = 0; it < 4; ++it) {
            int c = it * 256 + tid;
            int row = c >> 4, cc = c & 15, swz = cc ^ (row & 15);
            int grow = bm0 + row;
            int4 va = make_int4(0, 0, 0, 0);
            if (grow < N_NODES) va = *(const int4*)(A + (size_t)grow * KDIM + h * 128 + cc * 8);
            *(int4*)(As + row * 128 + swz * 8) = va;
        }
        // stage B half: 128x128 bf16 = 2048 int4 (8/thread)
        #pragma unroll
        for (int it = 0; it < 8; ++it) {
            int c = it * 256 + tid;
            int row = c >> 4, cc = c & 15, swz = cc ^ (row & 15);
            int4 vb = *(const int4*)(B + (size_t)row * KDIM + h * 128 + cc * 8);
            *(int4*)(Bs + row * 128 + swz * 8) = vb;
        }
        __syncthreads();

        #pragma unroll
        for (int kk = 0; kk < 4; ++kk) {
            int chunk = kk * 4 + quad;
            int sw = (chunk ^ lrow) * 8;
            v8s a[2], b[4];
            #pragma unroll
            for (int t = 0; t < 2; ++t) a[t] = *(const v8s*)(As + (wm + t * 16 + lrow) * 128 + sw);
            #pragma unroll
            for (int t = 0; t < 4; ++t) b[t] = *(const v8s*)(Bs + (wn + t * 16 + lrow) * 128 + sw);
            #pragma unroll
            for (int ti = 0; ti < 2; ++ti)
                #pragma unroll
                for (int tj = 0; tj < 4; ++tj)
                    accr[ti][tj] = __builtin_amdgcn_mfma_f32_16x16x32_bf16(a[ti], b[tj], accr[ti][tj], 0, 0, 0);
        }
    }

    int fl = *flag;
    #pragma unroll
    for (int ti = 0; ti < 2; ++ti)
        #pragma unroll
        for (int reg = 0; reg < 4; ++reg) {
            int gm = bm0 + wm + ti * 16 + quad * 4 + reg;
            if (gm >= N_NODES) continue;
            #pragma unroll
            for (int tj = 0; tj < 4; ++tj) {
                int col = wn + tj * 16 + lrow;
                size_t idx = (size_t)gm * 128 + col;
                float v = fmaxf(accr[ti][tj][reg] + bf2f(bias[col]), 0.f);
                if (!final_out) hout[idx] = f2bf(v);
                else if (fl)    ((u16*)fout)[idx] = f2bf(v);
                else            ((float*)fout)[idx] = v;
            }
        }
}

__global__ void k_relemb(const void* __restrict__ src, void* __restrict__ out,
                         const int* __restrict__ flag) {
    int i = blockIdx.x * 256 + threadIdx.x;
    if (i >= N_REL * 128) return;
    size_t o = (size_t)N_NODES * 128 + i;
    if (*flag) ((u16*)out)[o]   = ((const u16*)src)[i];
    else       ((float*)out)[o] = ((const float*)src)[i];
}

// ---------------- launch ----------------
static inline size_t align_up(size_t x, size_t a) { return (x + a - 1) & ~(a - 1); }

extern "C" void kernel_launch(void* const* d_in, const int* in_sizes, int n_in,
                              void* d_out, int out_size, void* d_ws, size_t ws_size,
                              hipStream_t stream) {
    const int* ei = (const int*)d_in[1];
    const int* et = (const int*)d_in[2];

    char* ws = (char*)d_ws;
    size_t off = 0;
    int* flag    = (int*)(ws + off);  off = align_up(off + 4, 256);
    u16* Wbig    = (u16*)(ws + off);  off = align_up(off + (size_t)2 * 128 * KDIM * 2, 256);
    u16* bc      = (u16*)(ws + off);  off = align_up(off + 512, 256);
    int* deg     = (int*)(ws + off);  off += (size_t)N_NODES * 4;    // deg+cursor contiguous
    int* cursor  = (int*)(ws + off);  off = align_up(off + (size_t)N_NODES * 4, 256);
    int* rowptr  = (int*)(ws + off);  off = align_up(off + (size_t)(N_NODES + 1) * 4, 256);
    int* psum    = (int*)(ws + off);  off = align_up(off + (size_t)NB_SCAN * 4, 256);
    int* eval    = (int*)(ws + off);  off = align_up(off + (size_t)N_EDGES * 4, 256);
    u16* h       = (u16*)(ws + off);  off = align_up(off + (size_t)N_NODES * 128 * 2, 256);
    u16* aggAll  = (u16*)(ws + off);  off += (size_t)N_NODES * KDIM * 2;   // ~132 MB total
    (void)in_sizes; (void)n_in; (void)out_size; (void)ws_size;  // ws >= 157 MB verified rounds 3-4

    k_detect<<<1, 256, 0, stream>>>((const u32*)d_in[0], flag);
    k_prep_w<<<(2 * 128 * KDIM + 256 + 255) / 256, 256, 0, stream>>>(
        d_in[3], d_in[4], d_in[5], d_in[6], d_in[7], d_in[8], flag, Wbig, bc);

    k_zero_i32<<<(2 * N_NODES + 255) / 256, 256, 0, stream>>>(deg, 2 * N_NODES);
    k_count<<<(N_EDGES + 255) / 256, 256, 0, stream>>>(ei, deg);
    k_scan1<<<NB_SCAN, 256, 0, stream>>>(deg, rowptr, psum);
    k_scan2<<<1, 256, 0, stream>>>(psum);
    k_scan3<<<NB_SCAN, 256, 0, stream>>>(rowptr, psum);
    k_fill<<<(N_EDGES + 255) / 256, 256, 0, stream>>>(ei, et, rowptr, cursor, eval);

    int ggrid = (N_NODES + 63) / 64;    // 782
    for (int l = 0; l < 2; ++l) {
        const void* src = l ? (const void*)h : (const void*)d_in[0];
        k_agg_all<<<(N_NODES + 3) / 4, 256, 0, stream>>>(src, rowptr, eval, aggAll, l, flag);
        k_gemm_fused<<<ggrid, 256, 0, stream>>>(aggAll, Wbig + (size_t)l * 128 * KDIM,
                                                bc + l * 128, h, d_out, l, flag);
    }
    k_relemb<<<4, 256, 0, stream>>>(d_in[9], d_out, flag);
}